// Round 1
// baseline (436.066 us; speedup 1.0000x reference)
//
#include <hip/hip_runtime.h>

// PlaceCellNetwork forward: out = softmax(tanh([x,1] @ Wh^T + bh + prev @ Wf) @ Wo^T + bo)
// B=4M, IN=2, HID=20, OUT=10. Memory-bound: 352 MB HBM traffic -> ~56us floor.
//
// Strategy:
//  - repack kernel: fold bh into Wh, transpose Wf (column of Wf per h becomes
//    contiguous), copy Wo/bo -> contiguous block in d_ws (490 floats).
//  - main kernel: 1 row per thread per grid-stride iter. All weight reads are
//    wave-uniform, compile-time-constant indices off a const __restrict__
//    pointer -> compiler emits s_load -> SGPR operands in v_fma (scalar pipe
//    is free, no VGPR/LDS pressure).
//  - fast tanh via 1 - 2*rcp(1+exp(2x)) (saturates correctly at +/-inf),
//    fast softmax via __expf + v_rcp. Tolerance is 1.47e-2 absolute.

#define HID 20
#define OUT 10

__device__ __forceinline__ float fast_rcp(float x) {
    return __builtin_amdgcn_rcpf(x);
}

__global__ void repack_kernel(const float* __restrict__ Wh,
                              const float* __restrict__ bh,
                              const float* __restrict__ Wo,
                              const float* __restrict__ bo,
                              const float* __restrict__ Wf,
                              float* __restrict__ ws) {
    int t = threadIdx.x;
    // WhB[h][4] = {Wh[h][0], Wh[h][1], Wh[h][2]+bh[h], 0}   at ws[0..79]
    if (t < HID) {
        ws[4 * t + 0] = Wh[3 * t + 0];
        ws[4 * t + 1] = Wh[3 * t + 1];
        ws[4 * t + 2] = Wh[3 * t + 2] + bh[t];
        ws[4 * t + 3] = 0.0f;
    }
    // WfT[h][o] = Wf[o][h]  at ws[80..279]
    for (int i = t; i < HID * OUT; i += blockDim.x) {
        int h = i / OUT, o = i % OUT;
        ws[80 + i] = Wf[o * HID + h];
    }
    // Wo[o][h] as-is at ws[280..479]
    for (int i = t; i < OUT * HID; i += blockDim.x) {
        ws[280 + i] = Wo[i];
    }
    // bo at ws[480..489]
    if (t < OUT) ws[480 + t] = bo[t];
}

template <bool PACKED>
__global__ __launch_bounds__(256) void pcn_kernel(
    const float* __restrict__ x,
    const float* __restrict__ prev,
    const float* __restrict__ ws,   // packed weights (PACKED) or unused
    const float* __restrict__ Wh,
    const float* __restrict__ bh,
    const float* __restrict__ Wo,
    const float* __restrict__ bo,
    const float* __restrict__ Wf,
    float* __restrict__ out,
    int B) {
    int tid = blockIdx.x * blockDim.x + threadIdx.x;
    int stride = gridDim.x * blockDim.x;

    for (int r = tid; r < B; r += stride) {
        // ---- load inputs (coalesced 8B/lane) ----
        float2 xv = *reinterpret_cast<const float2*>(x + 2 * (long)r);
        float p[OUT];
        const float2* pr = reinterpret_cast<const float2*>(prev + (long)OUT * r);
#pragma unroll
        for (int j = 0; j < OUT / 2; ++j) {
            float2 t = pr[j];
            p[2 * j] = t.x;
            p[2 * j + 1] = t.y;
        }

        // ---- hidden = tanh(Wh x + bh + Wf^T prev) ----
        float h[HID];
#pragma unroll
        for (int i = 0; i < HID; ++i) {
            float acc;
            if (PACKED) {
                acc = ws[4 * i + 2];
                acc = fmaf(ws[4 * i + 0], xv.x, acc);
                acc = fmaf(ws[4 * i + 1], xv.y, acc);
#pragma unroll
                for (int o = 0; o < OUT; ++o)
                    acc = fmaf(ws[80 + OUT * i + o], p[o], acc);
            } else {
                acc = Wh[3 * i + 2] + bh[i];
                acc = fmaf(Wh[3 * i + 0], xv.x, acc);
                acc = fmaf(Wh[3 * i + 1], xv.y, acc);
#pragma unroll
                for (int o = 0; o < OUT; ++o)
                    acc = fmaf(Wf[o * HID + i], p[o], acc);
            }
            // tanh(a) = 1 - 2/(1 + e^{2a}); exact at saturation (inf -> 1)
            float e = __expf(2.0f * acc);
            h[i] = 1.0f - 2.0f * fast_rcp(1.0f + e);
        }

        // ---- logits = Wo h + bo ----
        float l[OUT];
#pragma unroll
        for (int o = 0; o < OUT; ++o) {
            float acc = PACKED ? ws[480 + o] : bo[o];
#pragma unroll
            for (int i = 0; i < HID; ++i) {
                float w = PACKED ? ws[280 + HID * o + i] : Wo[HID * o + i];
                acc = fmaf(w, h[i], acc);
            }
            l[o] = acc;
        }

        // ---- softmax ----
        float m = l[0];
#pragma unroll
        for (int o = 1; o < OUT; ++o) m = fmaxf(m, l[o]);
        float s = 0.0f;
#pragma unroll
        for (int o = 0; o < OUT; ++o) {
            l[o] = __expf(l[o] - m);
            s += l[o];
        }
        float rs = fast_rcp(s);

        // ---- store (8B/lane) ----
        float2* op = reinterpret_cast<float2*>(out + (long)OUT * r);
#pragma unroll
        for (int j = 0; j < OUT / 2; ++j) {
            float2 t;
            t.x = l[2 * j] * rs;
            t.y = l[2 * j + 1] * rs;
            op[j] = t;
        }
    }
}

extern "C" void kernel_launch(void* const* d_in, const int* in_sizes, int n_in,
                              void* d_out, int out_size, void* d_ws, size_t ws_size,
                              hipStream_t stream) {
    const float* x    = (const float*)d_in[0];
    const float* prev = (const float*)d_in[1];
    const float* Wh   = (const float*)d_in[2];
    const float* bh   = (const float*)d_in[3];
    const float* Wo   = (const float*)d_in[4];
    const float* bo   = (const float*)d_in[5];
    const float* Wf   = (const float*)d_in[6];
    float* out = (float*)d_out;

    int B = in_sizes[0] / 2;

    const int block = 256;
    const int grid = 2048;  // grid-stride; ~7.6 rows/thread

    if (ws_size >= 490 * sizeof(float)) {
        float* ws = (float*)d_ws;
        repack_kernel<<<1, 256, 0, stream>>>(Wh, bh, Wo, bo, Wf, ws);
        pcn_kernel<true><<<grid, block, 0, stream>>>(
            x, prev, ws, Wh, bh, Wo, bo, Wf, out, B);
    } else {
        pcn_kernel<false><<<grid, block, 0, stream>>>(
            x, prev, nullptr, Wh, bh, Wo, bo, Wf, out, B);
    }
}

// Round 2
// 99.696 us; speedup vs baseline: 4.3740x; 4.3740x over previous
//
#include <hip/hip_runtime.h>

// PlaceCellNetwork forward: out = softmax(tanh([x,1] @ Wh^T + bh + prev @ Wf) @ Wo^T + bo)
// B=4M, IN=2, HID=20, OUT=10.
//
// R2 redesign: round-1 ran at 436us with VGPR_Count=40 -> per-thread arrays
// almost certainly went to scratch (live state > 40 regs). This version has
// ZERO per-thread arrays: all state is named scalars via macro expansion, the
// hidden layer is STREAMED (h_i consumed into 10 logit accumulators
// immediately, never stored), and each thread does 2 rows so all global I/O
// is aligned float4 (x: 1 load, prev: 5 loads, out: 5 stores).
// Weights are repacked in d_ws (Wh+bias fused, Wf^T, Wo^T, bo) and read with
// wave-uniform compile-time offsets -> s_load -> SGPR operands.

#define HID 20
#define OUT 10

__device__ __forceinline__ float fast_rcp(float x) { return __builtin_amdgcn_rcpf(x); }
// tanh(a) = 1 - 2/(1 + e^{2a}); exact at +/-inf saturation.
__device__ __forceinline__ float fast_tanh(float a) {
    return 1.0f - 2.0f * fast_rcp(1.0f + __expf(2.0f * a));
}

__global__ void repack_kernel(const float* __restrict__ Wh, const float* __restrict__ bh,
                              const float* __restrict__ Wo, const float* __restrict__ bo,
                              const float* __restrict__ Wf, float* __restrict__ ws) {
    int t = threadIdx.x;
    // ws[4i+{0,1,2}] = {Wh[i][0], Wh[i][1], Wh[i][2]+bh[i]}          (0..79)
    if (t < HID) {
        ws[4 * t + 0] = Wh[3 * t + 0];
        ws[4 * t + 1] = Wh[3 * t + 1];
        ws[4 * t + 2] = Wh[3 * t + 2] + bh[t];
        ws[4 * t + 3] = 0.0f;
    }
    // ws[80+10i+o]  = WfT[i][o] = Wf[o][i]                           (80..279)
    // ws[280+10i+o] = WoT[i][o] = Wo[o][i]                           (280..479)
    if (t < HID * OUT) {
        int i = t / OUT, o = t % OUT;
        ws[80 + t]  = Wf[o * HID + i];
        ws[280 + t] = Wo[o * HID + i];
    }
    // ws[480+o] = bo[o]                                              (480..489)
    if (t < OUT) ws[480 + t] = bo[t];
}

template <bool PACKED>
__global__ __launch_bounds__(256) void pcn_kernel(
    const float* __restrict__ x, const float* __restrict__ prev,
    const float* __restrict__ w,
    const float* __restrict__ Wh, const float* __restrict__ bh,
    const float* __restrict__ Wo, const float* __restrict__ bo,
    const float* __restrict__ Wf,
    float* __restrict__ out, int B) {
    const long t = (long)blockIdx.x * blockDim.x + threadIdx.x;
    const long r0 = 2 * t;           // rows r0, r0+1 (B even -> always a pair)
    if (r0 >= B) return;

    // ---- inputs: fully aligned float4 (x: 16t bytes, prev/out: 80t bytes) ----
    const float4 xv = *reinterpret_cast<const float4*>(x + 2 * r0);   // x0a,x1a,x0b,x1b
    const float4* pp = reinterpret_cast<const float4*>(prev + 10 * r0);
    const float4 q0 = pp[0], q1 = pp[1], q2 = pp[2], q3 = pp[3], q4 = pp[4];

    const float pA0=q0.x, pA1=q0.y, pA2=q0.z, pA3=q0.w, pA4=q1.x,
                pA5=q1.y, pA6=q1.z, pA7=q1.w, pA8=q2.x, pA9=q2.y;
    const float pB0=q2.z, pB1=q2.w, pB2=q3.x, pB3=q3.y, pB4=q3.z,
                pB5=q3.w, pB6=q4.x, pB7=q4.y, pB8=q4.z, pB9=q4.w;

    // ---- logit accumulators, init = bo ----
    float lA0,lA1,lA2,lA3,lA4,lA5,lA6,lA7,lA8,lA9;
    float lB0,lB1,lB2,lB3,lB4,lB5,lB6,lB7,lB8,lB9;
#define INITL(o) { const float b = PACKED ? w[480 + o] : bo[o]; lA##o = b; lB##o = b; }
    INITL(0) INITL(1) INITL(2) INITL(3) INITL(4)
    INITL(5) INITL(6) INITL(7) INITL(8) INITL(9)
#undef INITL

    // ---- stream hidden units: a_i -> tanh -> accumulate into logits ----
#pragma unroll
    for (int i = 0; i < HID; ++i) {
        const float w0 = PACKED ? w[4 * i + 0] : Wh[3 * i + 0];
        const float w1 = PACKED ? w[4 * i + 1] : Wh[3 * i + 1];
        const float wb = PACKED ? w[4 * i + 2] : (Wh[3 * i + 2] + bh[i]);
        float aA = fmaf(w1, xv.y, wb); aA = fmaf(w0, xv.x, aA);
        float aB = fmaf(w1, xv.w, wb); aB = fmaf(w0, xv.z, aB);
#define FB(o) { const float wf = PACKED ? w[80 + 10 * i + o] : Wf[o * HID + i]; \
                aA = fmaf(wf, pA##o, aA); aB = fmaf(wf, pB##o, aB); }
        FB(0) FB(1) FB(2) FB(3) FB(4) FB(5) FB(6) FB(7) FB(8) FB(9)
#undef FB
        const float hA = fast_tanh(aA);
        const float hB = fast_tanh(aB);
#define LO(o) { const float wo_ = PACKED ? w[280 + 10 * i + o] : Wo[o * HID + i]; \
                lA##o = fmaf(wo_, hA, lA##o); lB##o = fmaf(wo_, hB, lB##o); }
        LO(0) LO(1) LO(2) LO(3) LO(4) LO(5) LO(6) LO(7) LO(8) LO(9)
#undef LO
    }

    // ---- softmax, row A then row B (max tree, exp, sum tree, rcp) ----
    const float mA = fmaxf(fmaxf(fmaxf(lA0, lA1), fmaxf(lA2, lA3)),
                           fmaxf(fmaxf(lA4, lA5),
                                 fmaxf(fmaxf(lA6, lA7), fmaxf(lA8, lA9))));
    lA0 = __expf(lA0 - mA); lA1 = __expf(lA1 - mA); lA2 = __expf(lA2 - mA);
    lA3 = __expf(lA3 - mA); lA4 = __expf(lA4 - mA); lA5 = __expf(lA5 - mA);
    lA6 = __expf(lA6 - mA); lA7 = __expf(lA7 - mA); lA8 = __expf(lA8 - mA);
    lA9 = __expf(lA9 - mA);
    const float sA = ((lA0 + lA1) + (lA2 + lA3)) +
                     (((lA4 + lA5) + (lA6 + lA7)) + (lA8 + lA9));
    const float rsA = fast_rcp(sA);

    const float mB = fmaxf(fmaxf(fmaxf(lB0, lB1), fmaxf(lB2, lB3)),
                           fmaxf(fmaxf(lB4, lB5),
                                 fmaxf(fmaxf(lB6, lB7), fmaxf(lB8, lB9))));
    lB0 = __expf(lB0 - mB); lB1 = __expf(lB1 - mB); lB2 = __expf(lB2 - mB);
    lB3 = __expf(lB3 - mB); lB4 = __expf(lB4 - mB); lB5 = __expf(lB5 - mB);
    lB6 = __expf(lB6 - mB); lB7 = __expf(lB7 - mB); lB8 = __expf(lB8 - mB);
    lB9 = __expf(lB9 - mB);
    const float sB = ((lB0 + lB1) + (lB2 + lB3)) +
                     (((lB4 + lB5) + (lB6 + lB7)) + (lB8 + lB9));
    const float rsB = fast_rcp(sB);

    // ---- store: 5 aligned float4 ----
    float4* op = reinterpret_cast<float4*>(out + 10 * r0);
    op[0] = make_float4(lA0 * rsA, lA1 * rsA, lA2 * rsA, lA3 * rsA);
    op[1] = make_float4(lA4 * rsA, lA5 * rsA, lA6 * rsA, lA7 * rsA);
    op[2] = make_float4(lA8 * rsA, lA9 * rsA, lB0 * rsB, lB1 * rsB);
    op[3] = make_float4(lB2 * rsB, lB3 * rsB, lB4 * rsB, lB5 * rsB);
    op[4] = make_float4(lB6 * rsB, lB7 * rsB, lB8 * rsB, lB9 * rsB);
}

extern "C" void kernel_launch(void* const* d_in, const int* in_sizes, int n_in,
                              void* d_out, int out_size, void* d_ws, size_t ws_size,
                              hipStream_t stream) {
    const float* x    = (const float*)d_in[0];
    const float* prev = (const float*)d_in[1];
    const float* Wh   = (const float*)d_in[2];
    const float* bh   = (const float*)d_in[3];
    const float* Wo   = (const float*)d_in[4];
    const float* bo   = (const float*)d_in[5];
    const float* Wf   = (const float*)d_in[6];
    float* out = (float*)d_out;

    const int B = in_sizes[0] / 2;
    const int block = 256;
    const int grid = (B / 2 + block - 1) / block;  // 2 rows per thread

    if (ws_size >= 490 * sizeof(float)) {
        float* ws = (float*)d_ws;
        repack_kernel<<<1, 256, 0, stream>>>(Wh, bh, Wo, bo, Wf, ws);
        pcn_kernel<true><<<grid, block, 0, stream>>>(
            x, prev, ws, Wh, bh, Wo, bo, Wf, out, B);
    } else {
        pcn_kernel<false><<<grid, block, 0, stream>>>(
            x, prev, nullptr, Wh, bh, Wo, bo, Wf, out, B);
    }
}